// Round 9
// baseline (15717.294 us; speedup 1.0000x reference)
//
#include <hip/hip_runtime.h>
#include <math.h>

// T=64, B=128, H=256, C=256, K=8, L=3. One block = one sample, 512 threads.
// Map: u = tid&255 (unit/col, wave-consecutive), pg = tid>>8, rows pg*4+i.
// LDS A-reads are wave-uniform broadcasts (0 conflicts); global W coalesced.
// gemm: 6-stage rolling W prefetch + 2-stage A prefetch; packed v_pk_fma_f32.
// NOTE: __launch_bounds__ 2nd arg behaves CUDA-style (min blocks/CU) here —
// use amdgpu_waves_per_eu(2,2) to open a 256-VGPR budget (R6/R7/R8 evidence).
static constexpr size_t O_EMBW  = 0;         // [256 cls][1024 (u*4+g)]  emb@Wih0^T + b0
static constexpr size_t O_WPT   = 262144;    // [256 k][256 c]
static constexpr size_t O_WIHT  = 327680;    // [3][256 k][1024 (u*4+g)]
static constexpr size_t O_WHHT  = 1114112;   // [3][256 k][1024 (u*4+g)]
static constexpr size_t O_BIASC = 1900544;   // [3][256 u][4 g]  bih+bhh
// total 1903616 floats ≈ 7.6 MB

typedef float f2 __attribute__((ext_vector_type(2)));
__device__ __forceinline__ f2 fma2(f2 a, f2 b, f2 c){ return __builtin_elementwise_fma(a,b,c); }
__device__ __forceinline__ float sigf(float x){ return 1.0f/(1.0f + expf(-x)); }

// ---------------- one-time prep: transposes + combined biases ----------------
__global__ __launch_bounds__(256) void k_prep(
    const float* __restrict__ Wih, const float* __restrict__ Whh,
    const float* __restrict__ Wp,  const float* __restrict__ bih,
    const float* __restrict__ bhh,
    float* __restrict__ wihT, float* __restrict__ whhT,
    float* __restrict__ WpT, float* __restrict__ biasC)
{
  const int NT = 786432;
  const int TOTAL = 2*NT + 65536 + 3072;
  int stride = gridDim.x * blockDim.x;
  for (int i = blockIdx.x*blockDim.x + threadIdx.x; i < TOTAL; i += stride){
    if (i < NT){
      int l = i / 262144, r = i % 262144;      // r = row*256 + k
      int row = r >> 8, k = r & 255;
      int g = row >> 8, uu = row & 255;
      wihT[(size_t)l*262144 + (k<<10) + (uu<<2) + g] = Wih[i];
    } else if (i < 2*NT){
      int j = i - NT;
      int l = j / 262144, r = j % 262144;
      int row = r >> 8, k = r & 255;
      int g = row >> 8, uu = row & 255;
      whhT[(size_t)l*262144 + (k<<10) + (uu<<2) + g] = Whh[j];
    } else if (i < 2*NT + 65536){
      int j = i - 2*NT; int c = j >> 8, k = j & 255;
      WpT[(k<<8) + c] = Wp[j];
    } else {
      int j = i - 2*NT - 65536;          // [3][256][4]
      int l = j >> 10; int cg = j & 1023, uu = cg >> 2, g = cg & 3;
      biasC[j] = bih[l*1024 + g*256 + uu] + bhh[l*1024 + g*256 + uu];
    }
  }
}

// ------------- one-time: embW[cls][u*4+g] = emb@Wih0^T + bih0 + bhh0 ---------
__global__ __launch_bounds__(256) void k_embW(
    const float* __restrict__ emb, const float* __restrict__ wih0T,
    const float* __restrict__ bih, const float* __restrict__ bhh,
    float* __restrict__ embW)
{
  const int cls = blockIdx.x, uu = threadIdx.x;
  const float* er = emb + cls*256;
  float a0=0.f,a1=0.f,a2=0.f,a3=0.f;
  for (int k=0;k<256;k++){
    float ev = er[k];
    float4 w = *(const float4*)&wih0T[k*1024 + uu*4];
    a0 = fmaf(ev, w.x, a0); a1 = fmaf(ev, w.y, a1);
    a2 = fmaf(ev, w.z, a2); a3 = fmaf(ev, w.w, a3);
  }
  a0 += bih[uu]       + bhh[uu];
  a1 += bih[256+uu]   + bhh[256+uu];
  a2 += bih[512+uu]   + bhh[512+uu];
  a3 += bih[768+uu]   + bhh[768+uu];
  *(float4*)&embW[cls*1024 + uu*4] = make_float4(a0,a1,a2,a3);
}

// ---------------- the whole decode: 1 block = 1 sample, 512 threads ----------
__global__
__attribute__((amdgpu_flat_work_group_size(512,512)))
__attribute__((amdgpu_waves_per_eu(2,2)))
void k_decode(
    const float* __restrict__ x,      // [64][128][256]
    const float* __restrict__ WpT,    // [256 k][256 c]
    const float* __restrict__ wihT,   // [3][256 k][1024]
    const float* __restrict__ whhT,   // [3][256 k][1024]
    const float* __restrict__ biasC,  // [3][256 u][4 g]
    const float* __restrict__ embW,   // [256 cls][1024]
    const float* __restrict__ bp,     // [256]
    float* __restrict__ out)
{
  __shared__ float hS[3*2048];   // h[l][row][u]          24 KB
  __shared__ float cS[2048];     // staged c_old[row][u]   8 KB
  __shared__ float st[2048];     // state[row][u]          8 KB
  __shared__ float jnt[2048];    // logits / joint         8 KB
  __shared__ float pfx[8];
  __shared__ float red[8];  __shared__ int redi[8];
  __shared__ float sVal[8]; __shared__ int sPrev[8], sCls[8];
  __shared__ short prevH[512], clsH[512];

  const int tid = threadIdx.x;
  const int b   = blockIdx.x;
  const int u   = tid & 255;        // unit / class col — consecutive within wave
  const int pg  = tid >> 8;         // row group: rows pg*4 + 0..3 (wave-uniform)
  const int r0_ = pg*4;
  const int wv  = tid >> 6, lane = tid & 63;

  float creg[3][4];   // c[l] for rows r0_+0..3, unit u

  // ---- init: x0 into cS[0..255]; st broadcast; prefix ----
  if (tid < 64) *(float4*)&cS[tid*4] = *(const float4*)&x[(size_t)b*256 + tid*4];
  if (tid < 8)  pfx[tid] = (tid==0) ? 0.0f : -1e30f;
  __syncthreads();
  {
    float v = cS[u];
    #pragma unroll
    for (int i=0;i<4;i++) st[(r0_+i)*256 + u] = v;
  }
  __syncthreads();

  // ---- init LSTM from zero state: gates = in @ wihT_l + (bih+bhh), M=1 ----
  for (int l=0; l<3; l++){
    if (tid < 256){
      const int u2 = tid;
      const float* Wg = wihT + (size_t)l*262144;
      float acc0=0.f, acc1=0.f, acc2=0.f, acc3=0.f;
      for (int kc=0; kc<256; kc+=4){
        float4 a4 = *(const float4*)&cS[kc];
        float4 w0 = *(const float4*)&Wg[(size_t)(kc+0)*1024 + u2*4];
        float4 w1 = *(const float4*)&Wg[(size_t)(kc+1)*1024 + u2*4];
        float4 w2 = *(const float4*)&Wg[(size_t)(kc+2)*1024 + u2*4];
        float4 w3 = *(const float4*)&Wg[(size_t)(kc+3)*1024 + u2*4];
        acc0=fmaf(a4.x,w0.x,acc0); acc0=fmaf(a4.y,w1.x,acc0); acc0=fmaf(a4.z,w2.x,acc0); acc0=fmaf(a4.w,w3.x,acc0);
        acc1=fmaf(a4.x,w0.y,acc1); acc1=fmaf(a4.y,w1.y,acc1); acc1=fmaf(a4.z,w2.y,acc1); acc1=fmaf(a4.w,w3.y,acc1);
        acc2=fmaf(a4.x,w0.z,acc2); acc2=fmaf(a4.y,w1.z,acc2); acc2=fmaf(a4.z,w2.z,acc2); acc2=fmaf(a4.w,w3.z,acc2);
        acc3=fmaf(a4.x,w0.w,acc3); acc3=fmaf(a4.y,w1.w,acc3); acc3=fmaf(a4.z,w2.w,acc3); acc3=fmaf(a4.w,w3.w,acc3);
      }
      float4 bs = *(const float4*)&biasC[(l*256+u2)*4];
      float gi = acc0+bs.x, gg = acc2+bs.z, go = acc3+bs.w;  // c_old=0
      float cn = sigf(gi)*tanhf(gg);
      float hn = sigf(go)*tanhf(cn);
      jnt[u2] = hn; jnt[256+u2] = cn;
    }
    __syncthreads();
    {
      float hv = jnt[u], cv = jnt[256+u];
      #pragma unroll
      for (int i=0;i<4;i++){ hS[l*2048 + (r0_+i)*256 + u] = hv; creg[l][i] = cv; }
    }
    __syncthreads();
    if (tid < 256) cS[tid] = jnt[tid];   // next layer's input row
    __syncthreads();
  }

  // GEMM: 4 rows (LDS broadcast) x 4 gate-cols of unit u, K=256.
  // 6-stage W prefetch (24 float4) + 2-stage A prefetch (8 float4) ≈ 176 VGPR.
  // acc2: per row i, acc2[i*2]={gate_i,gate_f}, acc2[i*2+1]={gate_g,gate_o}.
  auto gemm_part = [&](const float* hbase, const int* ro,
                       const float* Wg, f2* acc2){
    const float* Wr = Wg + u*4;
    float4 wst[6][4];
    #pragma unroll
    for (int s=0; s<6; s++){
      const float* Wn = Wr + (size_t)(s*4)*1024;
      wst[s][0]=*(const float4*)&Wn[0];    wst[s][1]=*(const float4*)&Wn[1024];
      wst[s][2]=*(const float4*)&Wn[2048]; wst[s][3]=*(const float4*)&Wn[3072];
    }
    float4 ast[2][4];
    #pragma unroll
    for (int s2=0; s2<2; s2++){
      #pragma unroll
      for (int i=0;i<4;i++) ast[s2][i] = *(const float4*)&hbase[ro[i] + s2*4];
    }

    auto macblk = [&](const float4& wk0, const float4& wk1, const float4& wk2,
                      const float4& wk3, const float4& a0, const float4& a1,
                      const float4& a2, const float4& a3){
      const float A4[4][4] = {{a0.x,a0.y,a0.z,a0.w},{a1.x,a1.y,a1.z,a1.w},
                              {a2.x,a2.y,a2.z,a2.w},{a3.x,a3.y,a3.z,a3.w}};
      const float4 wk[4] = {wk0,wk1,wk2,wk3};
      #pragma unroll
      for (int kk=0;kk<4;kk++){
        f2 wlo = {wk[kk].x, wk[kk].y};
        f2 whi = {wk[kk].z, wk[kk].w};
        #pragma unroll
        for (int i=0;i<4;i++){
          f2 av = {A4[i][kk], A4[i][kk]};
          acc2[i*2+0] = fma2(av, wlo, acc2[i*2+0]);
          acc2[i*2+1] = fma2(av, whi, acc2[i*2+1]);
        }
      }
    };

    #pragma unroll 1
    for (int kc=0; kc<216; kc+=24){          // consume k 0..212, refill W to 236, A to 220
      #pragma unroll
      for (int s=0; s<6; s++){
        const int kcur = kc + s*4;
        const int a = (kcur>>2)&1;
        float4 wk0=wst[s][0], wk1=wst[s][1], wk2=wst[s][2], wk3=wst[s][3];
        float4 a0=ast[a][0], a1=ast[a][1], a2=ast[a][2], a3=ast[a][3];
        const float* Wn = Wr + (size_t)(kcur+24)*1024;
        wst[s][0]=*(const float4*)&Wn[0];    wst[s][1]=*(const float4*)&Wn[1024];
        wst[s][2]=*(const float4*)&Wn[2048]; wst[s][3]=*(const float4*)&Wn[3072];
        #pragma unroll
        for (int i=0;i<4;i++) ast[a][i] = *(const float4*)&hbase[ro[i] + kcur + 8];
        macblk(wk0,wk1,wk2,wk3, a0,a1,a2,a3);
      }
    }
    // tail A: consume k=216..236; refill W stages 0..3 with k=240..252; A rolls on
    #pragma unroll
    for (int s=0; s<6; s++){
      const int kcur = 216 + s*4;
      const int a = (kcur>>2)&1;
      float4 wk0=wst[s][0], wk1=wst[s][1], wk2=wst[s][2], wk3=wst[s][3];
      float4 a0=ast[a][0], a1=ast[a][1], a2=ast[a][2], a3=ast[a][3];
      if (kcur+24 < 256){
        const float* Wn = Wr + (size_t)(kcur+24)*1024;
        wst[s][0]=*(const float4*)&Wn[0];    wst[s][1]=*(const float4*)&Wn[1024];
        wst[s][2]=*(const float4*)&Wn[2048]; wst[s][3]=*(const float4*)&Wn[3072];
      }
      #pragma unroll
      for (int i=0;i<4;i++) ast[a][i] = *(const float4*)&hbase[ro[i] + kcur + 8];
      macblk(wk0,wk1,wk2,wk3, a0,a1,a2,a3);
    }
    // tail B: consume k=240..252 from W stages 0..3; A refill guarded
    #pragma unroll
    for (int s=0; s<4; s++){
      const int kcur = 240 + s*4;
      const int a = (kcur>>2)&1;
      float4 wk0=wst[s][0], wk1=wst[s][1], wk2=wst[s][2], wk3=wst[s][3];
      float4 a0=ast[a][0], a1=ast[a][1], a2=ast[a][2], a3=ast[a][3];
      if (kcur+8 < 256){
        #pragma unroll
        for (int i=0;i<4;i++) ast[a][i] = *(const float4*)&hbase[ro[i] + kcur + 8];
      }
      macblk(wk0,wk1,wk2,wk3, a0,a1,a2,a3);
    }
  };

  // ---------------- 64 decode steps, all block-local ----------------
  for (int t=0; t<64; t++){
    __syncthreads();   // st stable

    // ---- proj: rows r0_..r0_+3, col u; 4-stage scalar W prefetch, packed rows ----
    {
      const float* A0 = st + (r0_+0)*256;
      const float* A1 = st + (r0_+1)*256;
      const float* A2 = st + (r0_+2)*256;
      const float* A3 = st + (r0_+3)*256;
      const float* Wc = WpT + u;
      f2 q01 = {0.f,0.f}, q23 = {0.f,0.f};
      float wstp[4][4];
      #pragma unroll
      for (int s=0;s<4;s++){
        #pragma unroll
        for (int q=0;q<4;q++) wstp[s][q] = Wc[(s*4+q)*256];
      }
      #pragma unroll 1
      for (int kc=0; kc<240; kc+=16){
        #pragma unroll
        for (int s=0;s<4;s++){
          const int kcur = kc + s*4;
          float w0=wstp[s][0], w1=wstp[s][1], w2=wstp[s][2], w3=wstp[s][3];
          #pragma unroll
          for (int q=0;q<4;q++) wstp[s][q] = Wc[(kcur+16+q)*256];
          float4 a0 = *(const float4*)&A0[kcur];
          float4 a1 = *(const float4*)&A1[kcur];
          float4 a2 = *(const float4*)&A2[kcur];
          float4 a3 = *(const float4*)&A3[kcur];
          const float wq[4] = {w0,w1,w2,w3};
          const float A01[4][2] = {{a0.x,a1.x},{a0.y,a1.y},{a0.z,a1.z},{a0.w,a1.w}};
          const float A23[4][2] = {{a2.x,a3.x},{a2.y,a3.y},{a2.z,a3.z},{a2.w,a3.w}};
          #pragma unroll
          for (int kk=0;kk<4;kk++){
            f2 wb = {wq[kk], wq[kk]};
            f2 v01 = {A01[kk][0], A01[kk][1]};
            f2 v23 = {A23[kk][0], A23[kk][1]};
            q01 = fma2(v01, wb, q01);
            q23 = fma2(v23, wb, q23);
          }
        }
      }
      #pragma unroll
      for (int s=0;s<4;s++){
        const int kcur = 240 + s*4;
        float w0=wstp[s][0], w1=wstp[s][1], w2=wstp[s][2], w3=wstp[s][3];
        float4 a0 = *(const float4*)&A0[kcur];
        float4 a1 = *(const float4*)&A1[kcur];
        float4 a2 = *(const float4*)&A2[kcur];
        float4 a3 = *(const float4*)&A3[kcur];
        const float wq[4] = {w0,w1,w2,w3};
        const float A01[4][2] = {{a0.x,a1.x},{a0.y,a1.y},{a0.z,a1.z},{a0.w,a1.w}};
        const float A23[4][2] = {{a2.x,a3.x},{a2.y,a3.y},{a2.z,a3.z},{a2.w,a3.w}};
        #pragma unroll
        for (int kk=0;kk<4;kk++){
          f2 wb = {wq[kk], wq[kk]};
          f2 v01 = {A01[kk][0], A01[kk][1]};
          f2 v23 = {A23[kk][0], A23[kk][1]};
          q01 = fma2(v01, wb, q01);
          q23 = fma2(v23, wb, q23);
        }
      }
      float bpc = bp[u];
      jnt[(r0_+0)*256+u] = q01.x+bpc;
      jnt[(r0_+1)*256+u] = q01.y+bpc;
      jnt[(r0_+2)*256+u] = q23.x+bpc;
      jnt[(r0_+3)*256+u] = q23.y+bpc;
    }
    __syncthreads();

    // ---- log-softmax + prefix: wave wv handles beam-row wv ----
    {
      const int kb = wv;
      float4 v = *(const float4*)&jnt[kb*256 + lane*4];
      float m = fmaxf(fmaxf(v.x,v.y),fmaxf(v.z,v.w));
      for (int off=32;off;off>>=1) m = fmaxf(m, __shfl_down(m,off));
      m = __shfl(m, 0);
      double s = exp((double)v.x-(double)m)+exp((double)v.y-(double)m)
               + exp((double)v.z-(double)m)+exp((double)v.w-(double)m);
      for (int off=32;off;off>>=1) s += __shfl_down(s,off);
      s = __shfl(s, 0);
      double lse = log(s);
      float pf = pfx[kb];
      float4 o;
      o.x = (float)((double)v.x - (double)m - lse) + pf;
      o.y = (float)((double)v.y - (double)m - lse) + pf;
      o.z = (float)((double)v.z - (double)m - lse) + pf;
      o.w = (float)((double)v.w - (double)m - lse) + pf;
      *(float4*)&jnt[kb*256+lane*4] = o;
    }
    __syncthreads();

    // ---- top-8 of joint[2048]; stride-512 reads, (val, lowest-idx) ----
    for (int r=0;r<8;r++){
      float bv = -INFINITY; int bi = 0;
      #pragma unroll
      for (int i=0;i<4;i++){
        int idx = tid + 512*i; float vv = jnt[idx];
        if (vv > bv){ bv=vv; bi=idx; }     // i ascending => idx ascending
      }
      for (int off=32;off;off>>=1){
        float ov = __shfl_down(bv,off); int oi = __shfl_down(bi,off);
        if (ov>bv || (ov==bv && oi<bi)){ bv=ov; bi=oi; }
      }
      if (lane==0){ red[wv]=bv; redi[wv]=bi; }
      __syncthreads();
      if (tid==0){
        float BV=red[0]; int BI=redi[0];
        for (int j=1;j<8;j++) if (red[j]>BV || (red[j]==BV && redi[j]<BI)){BV=red[j];BI=redi[j];}
        sVal[r]=BV; sPrev[r]=BI>>8; sCls[r]=BI&255;
        jnt[BI] = -INFINITY;
      }
      __syncthreads();
    }
    if (tid<8){
      pfx[tid] = sVal[tid];
      prevH[t*8+tid] = (short)sPrev[tid];
      clsH[t*8+tid]  = (short)sCls[tid];
    }
    __syncthreads();

    // per-step beam bookkeeping for rows r0_..r0_+3 (wave-uniform)
    int clr[4], rog[4], rod[4];
    #pragma unroll
    for (int i=0;i<4;i++){
      clr[i] = sCls[r0_+i];
      rog[i] = sPrev[r0_+i]*256;
      rod[i] = (r0_+i)*256;
    }

    // ---- 3 LSTM layers ----
    #pragma unroll 1
    for (int l=0; l<3; l++){
      // stage c_old for the gather
      #pragma unroll
      for (int i=0;i<4;i++) cS[rod[i] + u] = creg[l][i];
      __syncthreads();   // cS visible; hS stable

      f2 acc2[8];
      #pragma unroll
      for (int i=0;i<8;i++) acc2[i] = (f2){0.f,0.f};
      if (l > 0){  // dense input: rows r0_..r0_+3 of hS[l-1]
        gemm_part(hS + (l-1)*2048, rod, wihT + (size_t)l*262144, acc2);
      }
      // recurrent: gathered rows of hS[l]
      gemm_part(hS + l*2048, rog, whhT + (size_t)l*262144, acc2);
      __syncthreads();   // all reads of hS[l] (old) and cS done

      // epilogue: LSTM cell for 4 (row, unit) cells
      {
        const int tn = (t < 63) ? (t+1) : 63;
        float xv = 0.f;
        if (l == 2) xv = x[(size_t)tn*32768 + b*256 + u];
        #pragma unroll
        for (int i=0;i<4;i++){
          float4 base = (l==0)
              ? *(const float4*)&embW[(size_t)clr[i]*1024 + u*4]
              : *(const float4*)&biasC[(l*256+u)*4];
          float co = cS[rog[i] + u];
          float gi = acc2[i*2+0].x + base.x;
          float gf = acc2[i*2+0].y + base.y;
          float gg = acc2[i*2+1].x + base.z;
          float go = acc2[i*2+1].y + base.w;
          float cn = sigf(gf)*co + sigf(gi)*tanhf(gg);
          float hn = sigf(go)*tanhf(cn);
          creg[l][i] = cn;
          hS[l*2048 + rod[i] + u] = hn;
          if (l == 2) st[rod[i] + u] = hn + xv;
        }
      }
      __syncthreads();   // epilogue writes visible
    }
  }

  // ---- backtrace choices + prefix ----
  if (tid < 8){
    int e = tid;
    for (int tt=63; tt>=0; --tt){
      out[(size_t)(b*8+tid)*64 + tt] = (float)clsH[tt*8+e];
      e = (int)prevH[tt*8+e];
    }
    out[65536 + b*8 + tid] = pfx[tid];
  }
}

extern "C" void kernel_launch(void* const* d_in, const int* in_sizes, int n_in,
                              void* d_out, int out_size, void* d_ws, size_t ws_size,
                              hipStream_t stream)
{
  const float* x   = (const float*)d_in[0];
  const float* emb = (const float*)d_in[1];
  const float* Wih = (const float*)d_in[2];
  const float* Whh = (const float*)d_in[3];
  const float* bih = (const float*)d_in[4];
  const float* bhh = (const float*)d_in[5];
  const float* Wp  = (const float*)d_in[6];
  const float* bp  = (const float*)d_in[7];
  float* ws = (float*)d_ws;

  float* embW  = ws + O_EMBW;
  float* WpT   = ws + O_WPT;
  float* wihT  = ws + O_WIHT;
  float* whhT  = ws + O_WHHT;
  float* biasC = ws + O_BIASC;

  k_prep<<<256,256,0,stream>>>(Wih,Whh,Wp,bih,bhh,wihT,whhT,WpT,biasC);
  k_embW<<<256,256,0,stream>>>(emb, wihT, bih, bhh, embW);
  k_decode<<<128,512,0,stream>>>(x, WpT, wihT, whhT, biasC, embW, bp, (float*)d_out);
}

// Round 10
// 6282.721 us; speedup vs baseline: 2.5017x; 2.5017x over previous
//
#include <hip/hip_runtime.h>
#include <math.h>

// T=64, B=128, H=256, C=256, K=8, L=3. One block = one sample, 512 threads.
// Map: u = tid&255 (unit/col, wave-consecutive), pg = tid>>8.
// LSTM GEMM: split-K — thread (u,pg) computes ALL 8 rows x 4 gate-cols over
// k in [pg*128, pg*128+128); partials combined via LDS (jnt) exchange.
// Halves per-wave global W-load count (L3-latency exposures) at equal VGPR.
// HARD CONSTRAINT (R6/R7/R9 evidence): allocator caps this kernel at 128
// VGPRs — any register pipeline must fit; spills show up as WRITE_SIZE blowup.
static constexpr size_t O_EMBW  = 0;         // [256 cls][1024 (u*4+g)]  emb@Wih0^T + b0
static constexpr size_t O_WPT   = 262144;    // [256 k][256 c]
static constexpr size_t O_WIHT  = 327680;    // [3][256 k][1024 (u*4+g)]
static constexpr size_t O_WHHT  = 1114112;   // [3][256 k][1024 (u*4+g)]
static constexpr size_t O_BIASC = 1900544;   // [3][256 u][4 g]  bih+bhh
// total 1903616 floats ≈ 7.6 MB

typedef float f2 __attribute__((ext_vector_type(2)));
__device__ __forceinline__ f2 fma2(f2 a, f2 b, f2 c){ return __builtin_elementwise_fma(a,b,c); }
__device__ __forceinline__ float sigf(float x){ return 1.0f/(1.0f + expf(-x)); }

// ---------------- one-time prep: transposes + combined biases ----------------
__global__ __launch_bounds__(256) void k_prep(
    const float* __restrict__ Wih, const float* __restrict__ Whh,
    const float* __restrict__ Wp,  const float* __restrict__ bih,
    const float* __restrict__ bhh,
    float* __restrict__ wihT, float* __restrict__ whhT,
    float* __restrict__ WpT, float* __restrict__ biasC)
{
  const int NT = 786432;
  const int TOTAL = 2*NT + 65536 + 3072;
  int stride = gridDim.x * blockDim.x;
  for (int i = blockIdx.x*blockDim.x + threadIdx.x; i < TOTAL; i += stride){
    if (i < NT){
      int l = i / 262144, r = i % 262144;      // r = row*256 + k
      int row = r >> 8, k = r & 255;
      int g = row >> 8, uu = row & 255;
      wihT[(size_t)l*262144 + (k<<10) + (uu<<2) + g] = Wih[i];
    } else if (i < 2*NT){
      int j = i - NT;
      int l = j / 262144, r = j % 262144;
      int row = r >> 8, k = r & 255;
      int g = row >> 8, uu = row & 255;
      whhT[(size_t)l*262144 + (k<<10) + (uu<<2) + g] = Whh[j];
    } else if (i < 2*NT + 65536){
      int j = i - 2*NT; int c = j >> 8, k = j & 255;
      WpT[(k<<8) + c] = Wp[j];
    } else {
      int j = i - 2*NT - 65536;          // [3][256][4]
      int l = j >> 10; int cg = j & 1023, uu = cg >> 2, g = cg & 3;
      biasC[j] = bih[l*1024 + g*256 + uu] + bhh[l*1024 + g*256 + uu];
    }
  }
}

// ------------- one-time: embW[cls][u*4+g] = emb@Wih0^T + bih0 + bhh0 ---------
__global__ __launch_bounds__(256) void k_embW(
    const float* __restrict__ emb, const float* __restrict__ wih0T,
    const float* __restrict__ bih, const float* __restrict__ bhh,
    float* __restrict__ embW)
{
  const int cls = blockIdx.x, uu = threadIdx.x;
  const float* er = emb + cls*256;
  float a0=0.f,a1=0.f,a2=0.f,a3=0.f;
  for (int k=0;k<256;k++){
    float ev = er[k];
    float4 w = *(const float4*)&wih0T[k*1024 + uu*4];
    a0 = fmaf(ev, w.x, a0); a1 = fmaf(ev, w.y, a1);
    a2 = fmaf(ev, w.z, a2); a3 = fmaf(ev, w.w, a3);
  }
  a0 += bih[uu]       + bhh[uu];
  a1 += bih[256+uu]   + bhh[256+uu];
  a2 += bih[512+uu]   + bhh[512+uu];
  a3 += bih[768+uu]   + bhh[768+uu];
  *(float4*)&embW[cls*1024 + uu*4] = make_float4(a0,a1,a2,a3);
}

// ---------------- the whole decode: 1 block = 1 sample, 512 threads ----------
__global__
__attribute__((amdgpu_flat_work_group_size(512,512)))
void k_decode(
    const float* __restrict__ x,      // [64][128][256]
    const float* __restrict__ WpT,    // [256 k][256 c]
    const float* __restrict__ wihT,   // [3][256 k][1024]
    const float* __restrict__ whhT,   // [3][256 k][1024]
    const float* __restrict__ biasC,  // [3][256 u][4 g]
    const float* __restrict__ embW,   // [256 cls][1024]
    const float* __restrict__ bp,     // [256]
    float* __restrict__ out)
{
  __shared__ float hS[3*2048];   // h[l][row][u]          24 KB
  __shared__ float cS[2048];     // staged c_old[row][u]   8 KB
  __shared__ float st[2048];     // state[row][u]          8 KB
  __shared__ float jnt[2048];    // logits / joint / gate-partial exchange  8 KB
  __shared__ float pfx[8];
  __shared__ float red[8];  __shared__ int redi[8];
  __shared__ float sVal[8]; __shared__ int sPrev[8], sCls[8];
  __shared__ short prevH[512], clsH[512];

  const int tid = threadIdx.x;
  const int b   = blockIdx.x;
  const int u   = tid & 255;        // unit / class col — consecutive within wave
  const int pg  = tid >> 8;         // k-half (LSTM) / row-half owner (epilogue, proj)
  const int r0_ = pg*4;
  const int wv  = tid >> 6, lane = tid & 63;

  float creg[3][4];   // c[l] for rows r0_+0..3, unit u (owner rows, as R8)

  // ---- init: x0 into cS[0..255]; st broadcast; prefix ----
  if (tid < 64) *(float4*)&cS[tid*4] = *(const float4*)&x[(size_t)b*256 + tid*4];
  if (tid < 8)  pfx[tid] = (tid==0) ? 0.0f : -1e30f;
  __syncthreads();
  {
    float v = cS[u];
    #pragma unroll
    for (int i=0;i<4;i++) st[(r0_+i)*256 + u] = v;
  }
  __syncthreads();

  // ---- init LSTM from zero state: gates = in @ wihT_l + (bih+bhh), M=1 ----
  for (int l=0; l<3; l++){
    if (tid < 256){
      const int u2 = tid;
      const float* Wg = wihT + (size_t)l*262144;
      float acc0=0.f, acc1=0.f, acc2=0.f, acc3=0.f;
      for (int kc=0; kc<256; kc+=4){
        float4 a4 = *(const float4*)&cS[kc];
        float4 w0 = *(const float4*)&Wg[(size_t)(kc+0)*1024 + u2*4];
        float4 w1 = *(const float4*)&Wg[(size_t)(kc+1)*1024 + u2*4];
        float4 w2 = *(const float4*)&Wg[(size_t)(kc+2)*1024 + u2*4];
        float4 w3 = *(const float4*)&Wg[(size_t)(kc+3)*1024 + u2*4];
        acc0=fmaf(a4.x,w0.x,acc0); acc0=fmaf(a4.y,w1.x,acc0); acc0=fmaf(a4.z,w2.x,acc0); acc0=fmaf(a4.w,w3.x,acc0);
        acc1=fmaf(a4.x,w0.y,acc1); acc1=fmaf(a4.y,w1.y,acc1); acc1=fmaf(a4.z,w2.y,acc1); acc1=fmaf(a4.w,w3.y,acc1);
        acc2=fmaf(a4.x,w0.z,acc2); acc2=fmaf(a4.y,w1.z,acc2); acc2=fmaf(a4.z,w2.z,acc2); acc2=fmaf(a4.w,w3.z,acc2);
        acc3=fmaf(a4.x,w0.w,acc3); acc3=fmaf(a4.y,w1.w,acc3); acc3=fmaf(a4.z,w2.w,acc3); acc3=fmaf(a4.w,w3.w,acc3);
      }
      float4 bs = *(const float4*)&biasC[(l*256+u2)*4];
      float gi = acc0+bs.x, gg = acc2+bs.z, go = acc3+bs.w;  // c_old=0
      float cn = sigf(gi)*tanhf(gg);
      float hn = sigf(go)*tanhf(cn);
      jnt[u2] = hn; jnt[256+u2] = cn;
    }
    __syncthreads();
    {
      float hv = jnt[u], cv = jnt[256+u];
      #pragma unroll
      for (int i=0;i<4;i++){ hS[l*2048 + (r0_+i)*256 + u] = hv; creg[l][i] = cv; }
    }
    __syncthreads();
    if (tid < 256) cS[tid] = jnt[tid];   // next layer's input row
    __syncthreads();
  }

  // LSTM GEMM (split-K): 8 rows x 4 gate-cols of unit u over 128 k's.
  // hbaseK / WgK are pre-offset by kbase. 2-stage rolling W prefetch (32 VGPR).
  // acc2: per row i, acc2[i*2]={gate_i,gate_f}, acc2[i*2+1]={gate_g,gate_o}.
  auto gemm_part = [&](const float* hbaseK, const int* ro,
                       const float* WgK, f2* acc2){
    const float* Wr = WgK + u*4;
    float4 wst[2][4];
    #pragma unroll
    for (int s=0; s<2; s++){
      const float* Wn = Wr + (size_t)(s*4)*1024;
      wst[s][0]=*(const float4*)&Wn[0];    wst[s][1]=*(const float4*)&Wn[1024];
      wst[s][2]=*(const float4*)&Wn[2048]; wst[s][3]=*(const float4*)&Wn[3072];
    }
    auto macblk = [&](const float4 wk[4], const float4 a[8]){
      #pragma unroll
      for (int kk=0;kk<4;kk++){
        f2 wlo = {wk[kk].x, wk[kk].y};
        f2 whi = {wk[kk].z, wk[kk].w};
        const float av4[8] = {
          kk==0?a[0].x:(kk==1?a[0].y:(kk==2?a[0].z:a[0].w)),
          kk==0?a[1].x:(kk==1?a[1].y:(kk==2?a[1].z:a[1].w)),
          kk==0?a[2].x:(kk==1?a[2].y:(kk==2?a[2].z:a[2].w)),
          kk==0?a[3].x:(kk==1?a[3].y:(kk==2?a[3].z:a[3].w)),
          kk==0?a[4].x:(kk==1?a[4].y:(kk==2?a[4].z:a[4].w)),
          kk==0?a[5].x:(kk==1?a[5].y:(kk==2?a[5].z:a[5].w)),
          kk==0?a[6].x:(kk==1?a[6].y:(kk==2?a[6].z:a[6].w)),
          kk==0?a[7].x:(kk==1?a[7].y:(kk==2?a[7].z:a[7].w))};
        #pragma unroll
        for (int i=0;i<8;i++){
          f2 av = {av4[i], av4[i]};
          acc2[i*2+0] = fma2(av, wlo, acc2[i*2+0]);
          acc2[i*2+1] = fma2(av, whi, acc2[i*2+1]);
        }
      }
    };
    #pragma unroll 1
    for (int kc=0; kc<120; kc+=8){           // consume k 0..119, refill to 127
      #pragma unroll
      for (int s=0; s<2; s++){
        const int kcur = kc + s*4;
        const float4 wk[4] = {wst[s][0], wst[s][1], wst[s][2], wst[s][3]};
        const float* Wn = Wr + (size_t)(kcur+8)*1024;
        wst[s][0]=*(const float4*)&Wn[0];    wst[s][1]=*(const float4*)&Wn[1024];
        wst[s][2]=*(const float4*)&Wn[2048]; wst[s][3]=*(const float4*)&Wn[3072];
        float4 a[8];
        #pragma unroll
        for (int i=0;i<8;i++) a[i] = *(const float4*)&hbaseK[ro[i] + kcur];
        macblk(wk, a);
      }
    }
    #pragma unroll
    for (int s=0; s<2; s++){                 // tail: k=120..127, no refill
      const int kcur = 120 + s*4;
      const float4 wk[4] = {wst[s][0], wst[s][1], wst[s][2], wst[s][3]};
      float4 a[8];
      #pragma unroll
      for (int i=0;i<8;i++) a[i] = *(const float4*)&hbaseK[ro[i] + kcur];
      macblk(wk, a);
    }
  };

  const int kbase = pg << 7;                 // this thread's k-half

  // ---------------- 64 decode steps, all block-local ----------------
  for (int t=0; t<64; t++){
    __syncthreads();   // st stable

    // ---- proj: rows r0_..r0_+3, col u; 4-stage scalar W prefetch (as R8) ----
    {
      const float* A0 = st + (r0_+0)*256;
      const float* A1 = st + (r0_+1)*256;
      const float* A2 = st + (r0_+2)*256;
      const float* A3 = st + (r0_+3)*256;
      const float* Wc = WpT + u;
      f2 q01 = {0.f,0.f}, q23 = {0.f,0.f};
      float wstp[4][4];
      #pragma unroll
      for (int s=0;s<4;s++){
        #pragma unroll
        for (int q=0;q<4;q++) wstp[s][q] = Wc[(s*4+q)*256];
      }
      #pragma unroll 1
      for (int kc=0; kc<240; kc+=16){
        #pragma unroll
        for (int s=0;s<4;s++){
          const int kcur = kc + s*4;
          float w0=wstp[s][0], w1=wstp[s][1], w2=wstp[s][2], w3=wstp[s][3];
          #pragma unroll
          for (int q=0;q<4;q++) wstp[s][q] = Wc[(kcur+16+q)*256];
          float4 a0 = *(const float4*)&A0[kcur];
          float4 a1 = *(const float4*)&A1[kcur];
          float4 a2 = *(const float4*)&A2[kcur];
          float4 a3 = *(const float4*)&A3[kcur];
          const float wq[4] = {w0,w1,w2,w3};
          const float A01[4][2] = {{a0.x,a1.x},{a0.y,a1.y},{a0.z,a1.z},{a0.w,a1.w}};
          const float A23[4][2] = {{a2.x,a3.x},{a2.y,a3.y},{a2.z,a3.z},{a2.w,a3.w}};
          #pragma unroll
          for (int kk=0;kk<4;kk++){
            f2 wb = {wq[kk], wq[kk]};
            f2 v01 = {A01[kk][0], A01[kk][1]};
            f2 v23 = {A23[kk][0], A23[kk][1]};
            q01 = fma2(v01, wb, q01);
            q23 = fma2(v23, wb, q23);
          }
        }
      }
      #pragma unroll
      for (int s=0;s<4;s++){
        const int kcur = 240 + s*4;
        float w0=wstp[s][0], w1=wstp[s][1], w2=wstp[s][2], w3=wstp[s][3];
        float4 a0 = *(const float4*)&A0[kcur];
        float4 a1 = *(const float4*)&A1[kcur];
        float4 a2 = *(const float4*)&A2[kcur];
        float4 a3 = *(const float4*)&A3[kcur];
        const float wq[4] = {w0,w1,w2,w3};
        const float A01[4][2] = {{a0.x,a1.x},{a0.y,a1.y},{a0.z,a1.z},{a0.w,a1.w}};
        const float A23[4][2] = {{a2.x,a3.x},{a2.y,a3.y},{a2.z,a3.z},{a2.w,a3.w}};
        #pragma unroll
        for (int kk=0;kk<4;kk++){
          f2 wb = {wq[kk], wq[kk]};
          f2 v01 = {A01[kk][0], A01[kk][1]};
          f2 v23 = {A23[kk][0], A23[kk][1]};
          q01 = fma2(v01, wb, q01);
          q23 = fma2(v23, wb, q23);
        }
      }
      float bpc = bp[u];
      jnt[(r0_+0)*256+u] = q01.x+bpc;
      jnt[(r0_+1)*256+u] = q01.y+bpc;
      jnt[(r0_+2)*256+u] = q23.x+bpc;
      jnt[(r0_+3)*256+u] = q23.y+bpc;
    }
    __syncthreads();

    // ---- log-softmax + prefix: wave wv handles beam-row wv ----
    {
      const int kb = wv;
      float4 v = *(const float4*)&jnt[kb*256 + lane*4];
      float m = fmaxf(fmaxf(v.x,v.y),fmaxf(v.z,v.w));
      for (int off=32;off;off>>=1) m = fmaxf(m, __shfl_down(m,off));
      m = __shfl(m, 0);
      double s = exp((double)v.x-(double)m)+exp((double)v.y-(double)m)
               + exp((double)v.z-(double)m)+exp((double)v.w-(double)m);
      for (int off=32;off;off>>=1) s += __shfl_down(s,off);
      s = __shfl(s, 0);
      double lse = log(s);
      float pf = pfx[kb];
      float4 o;
      o.x = (float)((double)v.x - (double)m - lse) + pf;
      o.y = (float)((double)v.y - (double)m - lse) + pf;
      o.z = (float)((double)v.z - (double)m - lse) + pf;
      o.w = (float)((double)v.w - (double)m - lse) + pf;
      *(float4*)&jnt[kb*256+lane*4] = o;
    }
    __syncthreads();

    // ---- top-8 of joint[2048]; stride-512 reads, (val, lowest-idx) ----
    for (int r=0;r<8;r++){
      float bv = -INFINITY; int bi = 0;
      #pragma unroll
      for (int i=0;i<4;i++){
        int idx = tid + 512*i; float vv = jnt[idx];
        if (vv > bv){ bv=vv; bi=idx; }     // i ascending => idx ascending
      }
      for (int off=32;off;off>>=1){
        float ov = __shfl_down(bv,off); int oi = __shfl_down(bi,off);
        if (ov>bv || (ov==bv && oi<bi)){ bv=ov; bi=oi; }
      }
      if (lane==0){ red[wv]=bv; redi[wv]=bi; }
      __syncthreads();
      if (tid==0){
        float BV=red[0]; int BI=redi[0];
        for (int j=1;j<8;j++) if (red[j]>BV || (red[j]==BV && redi[j]<BI)){BV=red[j];BI=redi[j];}
        sVal[r]=BV; sPrev[r]=BI>>8; sCls[r]=BI&255;
        jnt[BI] = -INFINITY;
      }
      __syncthreads();
    }
    if (tid<8){
      pfx[tid] = sVal[tid];
      prevH[t*8+tid] = (short)sPrev[tid];
      clsH[t*8+tid]  = (short)sCls[tid];
    }
    __syncthreads();

    // beam bookkeeping: all 8 rows for the gemm; owner rows for the epilogue
    int rog8[8], rod8[8];
    #pragma unroll
    for (int r=0;r<8;r++){ rog8[r] = sPrev[r]*256; rod8[r] = r*256; }
    int clrE[4];
    #pragma unroll
    for (int i=0;i<4;i++) clrE[i] = sCls[r0_+i];

    // ---- 3 LSTM layers (split-K + LDS reduction epilogue) ----
    #pragma unroll 1
    for (int l=0; l<3; l++){
      // stage c_old (thread's owner rows, as R8)
      #pragma unroll
      for (int i=0;i<4;i++) cS[(r0_+i)*256 + u] = creg[l][i];
      __syncthreads();   // cS visible; hS stable; jnt free

      f2 acc2[16];
      #pragma unroll
      for (int i=0;i<16;i++) acc2[i] = (f2){0.f,0.f};
      if (l > 0){  // dense input: all 8 rows of hS[l-1], this thread's k-half
        gemm_part(hS + (l-1)*2048 + kbase, rod8,
                  wihT + (size_t)l*262144 + (size_t)kbase*1024, acc2);
      }
      // recurrent: gathered rows of hS[l], this thread's k-half
      gemm_part(hS + l*2048 + kbase, rog8,
                whhT + (size_t)l*262144 + (size_t)kbase*1024, acc2);
      __syncthreads();   // all gemm reads of hS done before epilogue writes

      // epilogue: 4 quarter-rounds; partner ships partials via jnt,
      // owner (pg == H, same rows as R8) adds, runs the cell, stores.
      const int tn = (t < 63) ? (t+1) : 63;
      float xv = (l == 2) ? x[(size_t)tn*32768 + b*256 + u] : 0.f;
      #pragma unroll
      for (int q=0;q<4;q++){
        const int rA = q*2;
        const int H  = q>>1;
        if (pg != H){
          *(float4*)&jnt[u*4] = make_float4(
              acc2[rA*2].x, acc2[rA*2].y, acc2[rA*2+1].x, acc2[rA*2+1].y);
          *(float4*)&jnt[1024 + u*4] = make_float4(
              acc2[(rA+1)*2].x, acc2[(rA+1)*2].y, acc2[(rA+1)*2+1].x, acc2[(rA+1)*2+1].y);
        }
        __syncthreads();
        if (pg == H){
          #pragma unroll
          for (int rr=rA; rr<=rA+1; rr++){
            const int li = rr - r0_;   // 0..3 owner-local row index
            float4 part = *(const float4*)&jnt[(rr-rA)*1024 + u*4];
            float4 base = (l==0)
                ? *(const float4*)&embW[(size_t)clrE[li]*1024 + u*4]
                : *(const float4*)&biasC[(l*256+u)*4];
            float co = cS[rog8[rr] + u];
            float gi = acc2[rr*2+0].x + part.x + base.x;
            float gf = acc2[rr*2+0].y + part.y + base.y;
            float gg = acc2[rr*2+1].x + part.z + base.z;
            float go = acc2[rr*2+1].y + part.w + base.w;
            float cn = sigf(gf)*co + sigf(gi)*tanhf(gg);
            float hn = sigf(go)*tanhf(cn);
            creg[l][li] = cn;
            hS[l*2048 + rr*256 + u] = hn;
            if (l == 2) st[rr*256 + u] = hn + xv;
          }
        }
        __syncthreads();
      }
    }
  }

  // ---- backtrace choices + prefix ----
  if (tid < 8){
    int e = tid;
    for (int tt=63; tt>=0; --tt){
      out[(size_t)(b*8+tid)*64 + tt] = (float)clsH[tt*8+e];
      e = (int)prevH[tt*8+e];
    }
    out[65536 + b*8 + tid] = pfx[tid];
  }
}

extern "C" void kernel_launch(void* const* d_in, const int* in_sizes, int n_in,
                              void* d_out, int out_size, void* d_ws, size_t ws_size,
                              hipStream_t stream)
{
  const float* x   = (const float*)d_in[0];
  const float* emb = (const float*)d_in[1];
  const float* Wih = (const float*)d_in[2];
  const float* Whh = (const float*)d_in[3];
  const float* bih = (const float*)d_in[4];
  const float* bhh = (const float*)d_in[5];
  const float* Wp  = (const float*)d_in[6];
  const float* bp  = (const float*)d_in[7];
  float* ws = (float*)d_ws;

  float* embW  = ws + O_EMBW;
  float* WpT   = ws + O_WPT;
  float* wihT  = ws + O_WIHT;
  float* whhT  = ws + O_WHHT;
  float* biasC = ws + O_BIASC;

  k_prep<<<256,256,0,stream>>>(Wih,Whh,Wp,bih,bhh,wihT,whhT,WpT,biasC);
  k_embW<<<256,256,0,stream>>>(emb, wihT, bih, bhh, embW);
  k_decode<<<128,512,0,stream>>>(x, WpT, wihT, whhT, biasC, embW, bp, (float*)d_out);
}